// Round 1
// baseline (376.475 us; speedup 1.0000x reference)
//
#include <hip/hip_runtime.h>
#include <hip/hip_bf16.h>
#include <math.h>

typedef __attribute__((ext_vector_type(4))) float  f32x4;
typedef __attribute__((ext_vector_type(8))) __bf16 bf16x8;
typedef __attribute__((ext_vector_type(4))) unsigned int u32x4;

__device__ __forceinline__ unsigned short f2bu(float x) {
    __bf16 h = (__bf16)x;
    return __builtin_bit_cast(unsigned short, h);
}

__device__ __forceinline__ f32x4 MF(bf16x8 a, bf16x8 b, f32x4 c) {
    return __builtin_amdgcn_mfma_f32_16x16x32_bf16(a, b, c, 0, 0, 0);
}

__device__ __forceinline__ f32x4 zero4() { f32x4 z = {0.f, 0.f, 0.f, 0.f}; return z; }

// B-fragment (BT row-major, contiguous K): lane holds BT[row][k0..k0+7], f32 -> bf16
__device__ __forceinline__ bf16x8 bfrag_g(const float* W, int ldk, int row, int k0) {
    const float* p = W + (size_t)row * ldk + k0;
    bf16x8 r;
#pragma unroll
    for (int e = 0; e < 8; ++e) r[e] = (__bf16)p[e];
    return r;
}

// LDS layout (bytes)
#define VIN_OFF  0       // 3 * 16 rows * 256B  (bf16[16][128] per d) = 12288
#define H_OFF    12288   // 16 rows * 512B (bf16[16][256])            = 8192
#define S1_OFF   20480   // 16 rows * 256B                            = 4096
#define SOUT_OFF 24576   // 16 * f32
#define LDS_BYTES 24640

// A-fragment read from swizzled LDS tile: lane holds A[lane&15][k = kt*32 + (lane>>4)*8 + e]
__device__ __forceinline__ bf16x8 afrag(const unsigned char* base, int rb, int kt, int lane) {
    int row = lane & 15;
    int kb  = (kt << 6) + ((lane >> 4) << 4);
    u32x4 q = *(const u32x4*)(base + row * rb + (kb ^ ((row & 7) << 4)));
    return __builtin_bit_cast(bf16x8, q);
}

__device__ __forceinline__ unsigned long long pack4bf(f32x4 x) {
    return (unsigned long long)f2bu(x[0])
         | ((unsigned long long)f2bu(x[1]) << 16)
         | ((unsigned long long)f2bu(x[2]) << 32)
         | ((unsigned long long)f2bu(x[3]) << 48);
}

__global__ __launch_bounds__(512, 2) void eqsc_main(
    const float* __restrict__ S, const float* __restrict__ V,
    const float* __restrict__ u0w, const float* __restrict__ v0w,
    const float* __restrict__ a0w1, const float* __restrict__ a0b1,
    const float* __restrict__ a0w2, const float* __restrict__ a0b2,
    const float* __restrict__ u1w, const float* __restrict__ v1w,
    const float* __restrict__ a1w1, const float* __restrict__ a1b1,
    const float* __restrict__ a1w2, const float* __restrict__ a1b2,
    const float* __restrict__ outw, const float* __restrict__ outbp,
    float* __restrict__ sOut, int NT)
{
    __shared__ __align__(16) unsigned char lds[LDS_BYTES];
    const int tid  = threadIdx.x;
    const int lane = tid & 63;
    const int wv   = tid >> 6;        // wave 0..7, owns feature slice [wv*16, wv*16+16)
    const int l15  = lane & 15;
    const int lg   = lane >> 4;       // 0..3
    const int grow = wv * 16 + l15;   // this lane's output feature/col

    // ---- persistent weight fragments (bf16, in VGPRs) ----
    bf16x8 uw0f[4], vw0f[4], w2g0[4], w2s0[4], vw1f[4], w2g1[4];
    bf16x8 w1f0[8], w1f1[8];
#pragma unroll
    for (int kt = 0; kt < 4; ++kt) {
        int k0 = kt * 32 + lg * 8;
        uw0f[kt] = bfrag_g(u0w, 128, grow, k0);
        vw0f[kt] = bfrag_g(v0w, 128, grow, k0);
        w2g0[kt] = bfrag_g(a0w2, 128, grow, k0);
        w2s0[kt] = bfrag_g(a0w2, 128, 128 + grow, k0);
        vw1f[kt] = bfrag_g(v1w, 128, grow, k0);
        w2g1[kt] = bfrag_g(a1w2, 128, grow, k0);
    }
#pragma unroll
    for (int kt = 0; kt < 8; ++kt) {
        int k0 = kt * 32 + lg * 8;
        w1f0[kt] = bfrag_g(a0w1, 256, grow, k0);
        w1f1[kt] = bfrag_g(a1w1, 256, grow, k0);
    }
    const float b1_0 = a0b1[grow];
    const float b2g0 = a0b2[grow];
    const float b2s0 = a0b2[128 + grow];
    const float b1_1 = a1b1[grow];
    const float b2g1 = a1b2[grow];
    const float owv  = outw[grow];
    const float outb = outbp[0];

    for (int t = blockIdx.x; t < NT; t += gridDim.x) {
        const int a0 = t << 4;   // 16 atoms per tile
        if (tid < 16) *((float*)(lds + SOUT_OFF) + tid) = 0.f;
        // ---- stage V tile (16 atoms x 3 x 128 f32 -> bf16 LDS, swizzled) ----
#pragma unroll
        for (int j = 0; j < 3; ++j) {
            int c = tid + (j << 9);
            int d = c >> 9, rem = c & 511;
            int row = rem >> 5, k4 = (rem & 31) << 2;
            f32x4 x = *(const f32x4*)(V + (((size_t)(a0 + row) * 3 + d) << 7) + k4);
            *(unsigned long long*)(lds + VIN_OFF + (d << 12) + row * 256 +
                                   ((k4 << 1) ^ ((row & 7) << 4))) = pack4bf(x);
        }
        // ---- stage s tile into H[:,0:128] ----
        {
            int row = tid >> 5, k4 = (tid & 31) << 2;
            f32x4 x = *(const f32x4*)(S + (((size_t)(a0 + row)) << 7) + k4);
            *(unsigned long long*)(lds + H_OFF + row * 512 +
                                   ((k4 << 1) ^ ((row & 7) << 4))) = pack4bf(x);
        }
        __syncthreads();

        // ---- L0 v-phase: v1 = V@uw^T (kept in regs), v2 = V@vw^T -> norm^2 ----
        f32x4 v1a[3];
        f32x4 n2 = zero4();
#pragma unroll
        for (int d = 0; d < 3; ++d) {
            f32x4 v1 = zero4(), v2 = zero4();
#pragma unroll
            for (int kt = 0; kt < 4; ++kt) {
                bf16x8 a = afrag(lds + VIN_OFF + (d << 12), 256, kt, lane);
                v1 = MF(a, uw0f[kt], v1);
                v2 = MF(a, vw0f[kt], v2);
            }
            v1a[d] = v1;
#pragma unroll
            for (int e = 0; e < 4; ++e) { float x = v2[e] + 1e-8f; n2[e] += x * x; }
        }
#pragma unroll
        for (int e = 0; e < 4; ++e) {
            int row = lg * 4 + e;
            *(unsigned short*)(lds + H_OFF + row * 512 +
                ((256 + (grow << 1)) ^ ((row & 7) << 4))) = f2bu(sqrtf(n2[e]));
        }
        __syncthreads();

        // ---- L0 MLP1: h(256) -> 128, silu ----
        f32x4 m1 = zero4();
#pragma unroll
        for (int kt = 0; kt < 8; ++kt) m1 = MF(afrag(lds + H_OFF, 512, kt, lane), w1f0[kt], m1);
#pragma unroll
        for (int e = 0; e < 4; ++e) {
            float x = m1[e] + b1_0;
            float y = x / (1.f + __expf(-x));
            int row = lg * 4 + e;
            *(unsigned short*)(lds + S1_OFF + row * 256 +
                ((grow << 1) ^ ((row & 7) << 4))) = f2bu(y);
        }
        __syncthreads();

        // ---- L0 MLP2: 128 -> 256 (sg | ss); new s -> H[:,0:128]; vnew -> VIN ----
        f32x4 sg = zero4(), ssa = zero4();
#pragma unroll
        for (int kt = 0; kt < 4; ++kt) {
            bf16x8 a = afrag(lds + S1_OFF, 256, kt, lane);
            sg  = MF(a, w2g0[kt], sg);
            ssa = MF(a, w2s0[kt], ssa);
        }
#pragma unroll
        for (int e = 0; e < 4; ++e) {
            int row = lg * 4 + e;
            *(unsigned short*)(lds + H_OFF + row * 512 +
                ((grow << 1) ^ ((row & 7) << 4))) = f2bu(sg[e] + b2g0);
            float ssv = ssa[e] + b2s0;
#pragma unroll
            for (int d = 0; d < 3; ++d) {
                *(unsigned short*)(lds + VIN_OFF + (d << 12) + row * 256 +
                    ((grow << 1) ^ ((row & 7) << 4))) = f2bu(v1a[d][e] * ssv);
            }
        }
        __syncthreads();

        // ---- L1 v-phase (v2 only; v1 of layer 1 is dead code) ----
        n2 = zero4();
#pragma unroll
        for (int d = 0; d < 3; ++d) {
            f32x4 v2 = zero4();
#pragma unroll
            for (int kt = 0; kt < 4; ++kt)
                v2 = MF(afrag(lds + VIN_OFF + (d << 12), 256, kt, lane), vw1f[kt], v2);
#pragma unroll
            for (int e = 0; e < 4; ++e) { float x = v2[e] + 1e-8f; n2[e] += x * x; }
        }
#pragma unroll
        for (int e = 0; e < 4; ++e) {
            int row = lg * 4 + e;
            *(unsigned short*)(lds + H_OFF + row * 512 +
                ((256 + (grow << 1)) ^ ((row & 7) << 4))) = f2bu(sqrtf(n2[e]));
        }
        __syncthreads();

        // ---- L1 MLP1 ----
        m1 = zero4();
#pragma unroll
        for (int kt = 0; kt < 8; ++kt) m1 = MF(afrag(lds + H_OFF, 512, kt, lane), w1f1[kt], m1);
#pragma unroll
        for (int e = 0; e < 4; ++e) {
            float x = m1[e] + b1_1;
            float y = x / (1.f + __expf(-x));
            int row = lg * 4 + e;
            *(unsigned short*)(lds + S1_OFF + row * 256 +
                ((grow << 1) ^ ((row & 7) << 4))) = f2bu(y);
        }
        __syncthreads();

        // ---- L1 MLP2 (sg half only) + readout dot + tile reduction ----
        sg = zero4();
#pragma unroll
        for (int kt = 0; kt < 4; ++kt)
            sg = MF(afrag(lds + S1_OFF, 256, kt, lane), w2g1[kt], sg);
        float p[4];
#pragma unroll
        for (int e = 0; e < 4; ++e) p[e] = (sg[e] + b2g1) * owv;
#pragma unroll
        for (int off = 1; off < 16; off <<= 1) {
#pragma unroll
            for (int e = 0; e < 4; ++e) p[e] += __shfl_xor(p[e], off);
        }
        if (l15 == 0) {
#pragma unroll
            for (int e = 0; e < 4; ++e)
                atomicAdd((float*)(lds + SOUT_OFF) + lg * 4 + e, p[e]);
        }
        __syncthreads();
        if (tid < 16) sOut[a0 + tid] = *((float*)(lds + SOUT_OFF) + tid) + outb;
    }
}

// Dense masked pooling: y[b] = sum_a batch[b,a] * s_out[a]
__global__ __launch_bounds__(256) void eqsc_pool(const float* __restrict__ batch,
                                                 const float* __restrict__ s,
                                                 float* __restrict__ out,
                                                 int NA, int B, int CH)
{
    int b  = blockIdx.x % B;
    int ch = blockIdx.x / B;
    int a0 = ch * CH;
    int a1 = min(a0 + CH, NA);
    const float* br = batch + (size_t)b * NA;
    float acc = 0.f;
    for (int a = a0 + (threadIdx.x << 2); a < a1; a += 256 * 4) {
        f32x4 bb = *(const f32x4*)(br + a);
        f32x4 sv = *(const f32x4*)(s + a);
        acc += bb[0] * sv[0] + bb[1] * sv[1] + bb[2] * sv[2] + bb[3] * sv[3];
    }
#pragma unroll
    for (int off = 32; off > 0; off >>= 1) acc += __shfl_down(acc, off);
    __shared__ float wsum[4];
    if ((threadIdx.x & 63) == 0) wsum[threadIdx.x >> 6] = acc;
    __syncthreads();
    if (threadIdx.x == 0) atomicAdd(&out[b], wsum[0] + wsum[1] + wsum[2] + wsum[3]);
}

extern "C" void kernel_launch(void* const* d_in, const int* in_sizes, int n_in,
                              void* d_out, int out_size, void* d_ws, size_t ws_size,
                              hipStream_t stream)
{
    const float* S     = (const float*)d_in[0];
    const float* V     = (const float*)d_in[1];
    // d_in[2] = pos, unused by the reference
    const float* batch = (const float*)d_in[3];
    const float* u0w   = (const float*)d_in[4];
    const float* v0w   = (const float*)d_in[5];
    const float* a0w1  = (const float*)d_in[6];
    const float* a0b1  = (const float*)d_in[7];
    const float* a0w2  = (const float*)d_in[8];
    const float* a0b2  = (const float*)d_in[9];
    const float* u1w   = (const float*)d_in[10];
    const float* v1w   = (const float*)d_in[11];
    const float* a1w1  = (const float*)d_in[12];
    const float* a1b1  = (const float*)d_in[13];
    const float* a1w2  = (const float*)d_in[14];
    const float* a1b2  = (const float*)d_in[15];
    const float* outw  = (const float*)d_in[16];
    const float* outb  = (const float*)d_in[17];

    const int NA = in_sizes[0] / 128;
    const int NT = NA / 16;
    const int B  = in_sizes[3] / NA;
    float* sAtom = (float*)d_ws;

    hipMemsetAsync(d_out, 0, (size_t)out_size * sizeof(float), stream);

    eqsc_main<<<256, 512, 0, stream>>>(S, V, u0w, v0w, a0w1, a0b1, a0w2, a0b2,
                                       u1w, v1w, a1w1, a1b1, a1w2, a1b2,
                                       outw, outb, sAtom, NT);

    const int CH  = 16384;
    const int NCH = (NA + CH - 1) / CH;
    eqsc_pool<<<B * NCH, 256, 0, stream>>>(batch, sAtom, (float*)d_out, NA, B, CH);
}